// Round 1
// baseline (1530.762 us; speedup 1.0000x reference)
//
#include <hip/hip_runtime.h>
#include <math.h>

// Problem constants (reference file): N=100000, E=1600000, D_IN=D_OUT=128
#define D 128
constexpr float BN_EPS = 1e-5f;

// ---------------------------------------------------------------------------
// Kernel 1: SpMM scatter  agg[dst] += val * x[src]
// One 64-lane wave per edge; each lane handles a float2 (64*8B = 512B row).
// ---------------------------------------------------------------------------
__global__ __launch_bounds__(256) void spmm_kernel(
    const float* __restrict__ x,
    const int* __restrict__ esrc,
    const int* __restrict__ edst,
    const float* __restrict__ eval,
    float* __restrict__ agg,
    int E)
{
    int wave  = (blockIdx.x * blockDim.x + threadIdx.x) >> 6;
    int lane  = threadIdx.x & 63;
    int nwave = (gridDim.x * blockDim.x) >> 6;
    for (int e = wave; e < E; e += nwave) {
        int   s = esrc[e];          // broadcast loads (same addr across wave)
        int   d = edst[e];
        float v = eval[e];
        const float2 xv = ((const float2*)(x + (size_t)s * D))[lane];
        float* ar = agg + (size_t)d * D + lane * 2;
        atomicAdd(ar,     xv.x * v);
        atomicAdd(ar + 1, xv.y * v);
    }
}

// ---------------------------------------------------------------------------
// Kernel 2: h = agg @ W   (fp32 vector ALU; no fp32 MFMA on CDNA4)
// Block = 256 threads, computes 32 rows x 128 cols.
// W (64KB) + 32-row A tile (16KB) staged in LDS -> 80KB -> 2 blocks/CU.
// Thread (tx,ty): tx in [0,32) -> 4 cols, ty in [0,8) -> 4 rows (stride 8).
// ---------------------------------------------------------------------------
__global__ __launch_bounds__(256) void gemm_kernel(
    const float* __restrict__ A,
    const float* __restrict__ W,
    float* __restrict__ h,
    int n)
{
    __shared__ float sW[128 * 128];
    __shared__ float sA[32][128];

    const int tid = threadIdx.x;

    // stage W: 16384 floats = 4096 float4 / 256 threads = 16 each
    const float4* W4  = (const float4*)W;
    float4*       sW4 = (float4*)sW;
#pragma unroll
    for (int i = 0; i < 16; i++) sW4[tid + 256 * i] = W4[tid + 256 * i];

    // stage 32 rows of A: 4096 floats = 1024 float4 / 256 threads = 4 each
    const int row0 = blockIdx.x * 32;
    const float4* A4  = (const float4*)(A + (size_t)row0 * D);
    float4*       sA4 = (float4*)&sA[0][0];
#pragma unroll
    for (int i = 0; i < 4; i++) {
        int idx = tid + 256 * i;
        // guard (n=100000 is divisible by 32, so normally always in-bounds)
        sA4[idx] = ((size_t)row0 * D + idx * 4 < (size_t)n * D)
                       ? A4[idx] : make_float4(0.f, 0.f, 0.f, 0.f);
    }
    __syncthreads();

    const int tx = tid & 31;   // 32 col-groups of 4
    const int ty = tid >> 5;   // 8 row slots
    const int c0 = tx * 4;

    float acc[4][4] = {};
    for (int k = 0; k < 128; k++) {
        const float4 w = *(const float4*)&sW[k * 128 + c0];  // contiguous 512B/half-wave
#pragma unroll
        for (int j = 0; j < 4; j++) {
            const float a = sA[ty + 8 * j][k];  // 2-way same-bank: free
            acc[j][0] += a * w.x;
            acc[j][1] += a * w.y;
            acc[j][2] += a * w.z;
            acc[j][3] += a * w.w;
        }
    }

#pragma unroll
    for (int j = 0; j < 4; j++) {
        const int row = row0 + ty + 8 * j;
        if (row < n) {
            *(float4*)&h[(size_t)row * D + c0] =
                make_float4(acc[j][0], acc[j][1], acc[j][2], acc[j][3]);
        }
    }
}

// ---------------------------------------------------------------------------
// Kernel 3: per-column sum and sum-of-squares over the N rows of h.
// Block = 256 threads = 2 rows x 128 cols; per-thread register accumulation,
// then one atomicAdd per column pair per block into stats[256].
// ---------------------------------------------------------------------------
__global__ __launch_bounds__(256) void stats_kernel(
    const float* __restrict__ h,
    float* __restrict__ stats,   // [0..127]=sum, [128..255]=sumsq
    int n)
{
    __shared__ float ssum[256];
    __shared__ float ssq[256];
    const int tid  = threadIdx.x;
    const int col  = tid & 127;
    const int half = tid >> 7;

    float s = 0.f, q = 0.f;
    for (int r = blockIdx.x * 2 + half; r < n; r += gridDim.x * 2) {
        const float v = h[(size_t)r * D + col];
        s += v;
        q += v * v;
    }
    ssum[tid] = s;
    ssq[tid]  = q;
    __syncthreads();
    if (tid < 128) {
        atomicAdd(&stats[col],       ssum[tid] + ssum[tid + 128]);
        atomicAdd(&stats[128 + col], ssq[tid] + ssq[tid + 128]);
    }
}

// ---------------------------------------------------------------------------
// Kernel 4: in-place BatchNorm apply on h (= d_out).
// out = (h - mean) * rsqrt(var + eps) * gamma + beta
// NOTE: linear bias cancels under BN (per-column constant shift) -> omitted.
// ---------------------------------------------------------------------------
__global__ __launch_bounds__(256) void bn_apply_kernel(
    float* __restrict__ h,
    const float* __restrict__ stats,
    const float* __restrict__ gamma,
    const float* __restrict__ beta,
    int n)
{
    __shared__ float s_scale[128];
    __shared__ float s_shift[128];
    const int tid = threadIdx.x;
    if (tid < 128) {
        const float invn = 1.0f / (float)n;
        const float mean = stats[tid] * invn;
        const float var  = stats[128 + tid] * invn - mean * mean;
        const float inv  = rsqrtf(var + BN_EPS);
        const float g    = gamma[tid] * inv;
        s_scale[tid] = g;
        s_shift[tid] = beta[tid] - mean * g;
    }
    __syncthreads();

    float4* h4 = (float4*)h;
    const size_t total = (size_t)n * D / 4;
    const size_t stride = (size_t)gridDim.x * blockDim.x;
    for (size_t i = (size_t)blockIdx.x * blockDim.x + tid; i < total; i += stride) {
        float4 v = h4[i];
        const int c = (int)((i * 4) & (D - 1));
        v.x = v.x * s_scale[c]     + s_shift[c];
        v.y = v.y * s_scale[c + 1] + s_shift[c + 1];
        v.z = v.z * s_scale[c + 2] + s_shift[c + 2];
        v.w = v.w * s_scale[c + 3] + s_shift[c + 3];
        h4[i] = v;
    }
}

// ---------------------------------------------------------------------------
extern "C" void kernel_launch(void* const* d_in, const int* in_sizes, int n_in,
                              void* d_out, int out_size, void* d_ws, size_t ws_size,
                              hipStream_t stream)
{
    const float* x     = (const float*)d_in[0];
    const int*   esrc  = (const int*)d_in[1];
    const int*   edst  = (const int*)d_in[2];
    const float* evals = (const float*)d_in[3];
    const float* W     = (const float*)d_in[4];
    // d_in[5] = bias: unused — cancels exactly under BatchNorm.
    const float* gamma = (const float*)d_in[6];
    const float* beta  = (const float*)d_in[7];
    float* out = (float*)d_out;

    const int n = in_sizes[0] / D;   // 100000
    const int E = in_sizes[1];       // 1600000

    float* agg   = (float*)d_ws;                 // [n*D] fp32 = 51.2 MB
    float* stats = agg + (size_t)n * D;          // [256] fp32

    // zero agg + stats (ws is poisoned to 0xAA before every call)
    hipMemsetAsync(d_ws, 0, ((size_t)n * D + 256) * sizeof(float), stream);

    // 1) SpMM scatter into agg
    spmm_kernel<<<4096, 256, 0, stream>>>(x, esrc, edst, evals, agg, E);

    // 2) h = agg @ W  -> d_out
    gemm_kernel<<<(n + 31) / 32, 256, 0, stream>>>(agg, W, out, n);

    // 3) column stats of h
    stats_kernel<<<256, 256, 0, stream>>>(out, stats, n);

    // 4) in-place BN
    bn_apply_kernel<<<2048, 256, 0, stream>>>(out, stats, gamma, beta, n);
}

// Round 2
// 670.440 us; speedup vs baseline: 2.2832x; 2.2832x over previous
//
#include <hip/hip_runtime.h>
#include <math.h>

// Problem constants: N=100000, E=1600000, D_IN=D_OUT=128
#define D 128
constexpr float BN_EPS = 1e-5f;

// ---------------------------------------------------------------------------
// CSR build step 1: histogram of edge destinations.
// ---------------------------------------------------------------------------
__global__ __launch_bounds__(256) void hist_kernel(
    const int* __restrict__ edst, int* __restrict__ cnt, int E)
{
    int e = blockIdx.x * blockDim.x + threadIdx.x;
    if (e < E) atomicAdd(&cnt[edst[e]], 1);
}

// ---------------------------------------------------------------------------
// CSR build step 2: exclusive scan of cnt[n] -> rowptr[n]. Single block.
// Each of 1024 threads serially scans a contiguous chunk; block-level
// Hillis-Steele scan combines chunk sums.
// ---------------------------------------------------------------------------
__global__ __launch_bounds__(1024) void scan_kernel(
    const int* __restrict__ cnt, int* __restrict__ rowptr, int n)
{
    __shared__ int part[1024];
    const int tid = threadIdx.x;
    const int chunk = (n + 1023) / 1024;
    const int lo = tid * chunk;
    const int hi = min(lo + chunk, n);

    int s = 0;
    for (int i = lo; i < hi; i++) s += cnt[i];
    part[tid] = s;
    __syncthreads();
    for (int off = 1; off < 1024; off <<= 1) {
        int v = (tid >= off) ? part[tid - off] : 0;
        __syncthreads();
        if (tid >= off) part[tid] += v;
        __syncthreads();
    }
    int run = part[tid] - s;   // exclusive prefix of this chunk
    for (int i = lo; i < hi; i++) {
        rowptr[i] = run;
        run += cnt[i];
    }
}

// ---------------------------------------------------------------------------
// CSR build step 3: scatter edges into CSR order. Uses rowptr itself as the
// fill cursor: after this kernel rowptr[d] == start of row d+1, so row d
// spans [ d ? rowptr[d-1] : 0, rowptr[d] ).
// ---------------------------------------------------------------------------
__global__ __launch_bounds__(256) void scatter_kernel(
    const int* __restrict__ esrc, const int* __restrict__ edst,
    const float* __restrict__ evals,
    int* __restrict__ rowptr,
    int* __restrict__ csr_src, float* __restrict__ csr_val, int E)
{
    int e = blockIdx.x * blockDim.x + threadIdx.x;
    if (e < E) {
        int d = edst[e];
        int pos = atomicAdd(&rowptr[d], 1);
        csr_src[pos] = esrc[e];
        csr_val[pos] = evals[e];
    }
}

// ---------------------------------------------------------------------------
// CSR SpMM: one wave per dst row; lane handles a float2 (64*8B = 512B row).
// Register accumulation, single non-atomic write per row. 2-wide edge unroll
// for load-latency ILP.
// ---------------------------------------------------------------------------
__global__ __launch_bounds__(256) void spmm_csr_kernel(
    const float* __restrict__ x,
    const int* __restrict__ rowptr,   // post-scatter (shifted) form
    const int* __restrict__ csr_src,
    const float* __restrict__ csr_val,
    float* __restrict__ agg, int n)
{
    int wave = (blockIdx.x * blockDim.x + threadIdx.x) >> 6;
    int lane = threadIdx.x & 63;
    if (wave >= n) return;
    int start = (wave == 0) ? 0 : rowptr[wave - 1];
    int end   = rowptr[wave];

    float2 acc = make_float2(0.f, 0.f);
    int e = start;
    for (; e + 1 < end; e += 2) {
        int   s0 = csr_src[e];
        int   s1 = csr_src[e + 1];
        float v0 = csr_val[e];
        float v1 = csr_val[e + 1];
        float2 a = ((const float2*)(x + (size_t)s0 * D))[lane];
        float2 b = ((const float2*)(x + (size_t)s1 * D))[lane];
        acc.x += v0 * a.x + v1 * b.x;
        acc.y += v0 * a.y + v1 * b.y;
    }
    if (e < end) {
        int   s0 = csr_src[e];
        float v0 = csr_val[e];
        float2 a = ((const float2*)(x + (size_t)s0 * D))[lane];
        acc.x += v0 * a.x;
        acc.y += v0 * a.y;
    }
    ((float2*)(agg + (size_t)wave * D))[lane] = acc;
}

// ---------------------------------------------------------------------------
// Fallback SpMM (atomic scatter) if ws_size is too small for CSR arrays.
// ---------------------------------------------------------------------------
__global__ __launch_bounds__(256) void spmm_atomic_kernel(
    const float* __restrict__ x,
    const int* __restrict__ esrc, const int* __restrict__ edst,
    const float* __restrict__ eval, float* __restrict__ agg, int E)
{
    int wave  = (blockIdx.x * blockDim.x + threadIdx.x) >> 6;
    int lane  = threadIdx.x & 63;
    int nwave = (gridDim.x * blockDim.x) >> 6;
    for (int e = wave; e < E; e += nwave) {
        int   s = esrc[e];
        int   d = edst[e];
        float v = eval[e];
        const float2 xv = ((const float2*)(x + (size_t)s * D))[lane];
        float* ar = agg + (size_t)d * D + lane * 2;
        atomicAdd(ar,     xv.x * v);
        atomicAdd(ar + 1, xv.y * v);
    }
}

// ---------------------------------------------------------------------------
// GEMM h = agg @ W with fused per-column sum / sum-of-squares epilogue.
// Block = 256 threads -> 32 rows x 128 cols tile. W (64KB) + A tile (16KB)
// in LDS = 80KB -> 2 blocks/CU. Inner loop k-unrolled by 4, float4 LDS reads
// for both A (wave-broadcast) and W (contiguous).
// ---------------------------------------------------------------------------
__global__ __launch_bounds__(256) void gemm_stats_kernel(
    const float* __restrict__ A,
    const float* __restrict__ W,
    float* __restrict__ h,
    float* __restrict__ stats,   // [0..127]=colsum, [128..255]=colsumsq
    int n)
{
    __shared__ float sW[128 * 128];
    __shared__ float sA[32][128];

    const int tid = threadIdx.x;

    const float4* W4  = (const float4*)W;
    float4*       sW4 = (float4*)sW;
#pragma unroll
    for (int i = 0; i < 16; i++) sW4[tid + 256 * i] = W4[tid + 256 * i];

    const int row0 = blockIdx.x * 32;
    const float4* A4  = (const float4*)(A + (size_t)row0 * D);
    float4*       sA4 = (float4*)&sA[0][0];
#pragma unroll
    for (int i = 0; i < 4; i++) {
        int idx = tid + 256 * i;
        sA4[idx] = ((size_t)row0 * D + (size_t)idx * 4 < (size_t)n * D)
                       ? A4[idx] : make_float4(0.f, 0.f, 0.f, 0.f);
    }
    __syncthreads();

    const int tx = tid & 31;   // 32 col-groups of 4
    const int ty = tid >> 5;   // 8 row slots (rows ty, ty+8, ty+16, ty+24)
    const int c0 = tx * 4;

    float acc[4][4] = {};
    for (int k0 = 0; k0 < 128; k0 += 4) {
        float4 a[4];
#pragma unroll
        for (int j = 0; j < 4; j++)
            a[j] = *(const float4*)&sA[ty + 8 * j][k0];   // wave-broadcast
#pragma unroll
        for (int kk = 0; kk < 4; kk++) {
            const float4 w = *(const float4*)&sW[(k0 + kk) * 128 + c0];
            const float ak[4] = { kk == 0 ? a[0].x : kk == 1 ? a[0].y : kk == 2 ? a[0].z : a[0].w,
                                  kk == 0 ? a[1].x : kk == 1 ? a[1].y : kk == 2 ? a[1].z : a[1].w,
                                  kk == 0 ? a[2].x : kk == 1 ? a[2].y : kk == 2 ? a[2].z : a[2].w,
                                  kk == 0 ? a[3].x : kk == 1 ? a[3].y : kk == 2 ? a[3].z : a[3].w };
#pragma unroll
            for (int j = 0; j < 4; j++) {
                acc[j][0] += ak[j] * w.x;
                acc[j][1] += ak[j] * w.y;
                acc[j][2] += ak[j] * w.z;
                acc[j][3] += ak[j] * w.w;
            }
        }
    }

    // write h tile
#pragma unroll
    for (int j = 0; j < 4; j++) {
        const int row = row0 + ty + 8 * j;
        if (row < n)
            *(float4*)&h[(size_t)row * D + c0] =
                make_float4(acc[j][0], acc[j][1], acc[j][2], acc[j][3]);
    }

    // fused column stats: reuse sA as scratch (all reads of sA are done)
    __syncthreads();
    float* csum = &sA[0][0];
    float* csq  = csum + 128;
    if (tid < 128) { csum[tid] = 0.f; csq[tid] = 0.f; }
    __syncthreads();
#pragma unroll
    for (int c = 0; c < 4; c++) {
        float s = 0.f, q = 0.f;
#pragma unroll
        for (int j = 0; j < 4; j++) { s += acc[j][c]; q += acc[j][c] * acc[j][c]; }
        atomicAdd(&csum[c0 + c], s);
        atomicAdd(&csq[c0 + c], q);
    }
    __syncthreads();
    if (tid < 128) {
        atomicAdd(&stats[tid],       csum[tid]);
        atomicAdd(&stats[128 + tid], csq[tid]);
    }
}

// ---------------------------------------------------------------------------
// In-place BatchNorm apply. Linear bias cancels under BN -> omitted.
// ---------------------------------------------------------------------------
__global__ __launch_bounds__(256) void bn_apply_kernel(
    float* __restrict__ h,
    const float* __restrict__ stats,
    const float* __restrict__ gamma,
    const float* __restrict__ beta,
    int n)
{
    __shared__ float s_scale[128];
    __shared__ float s_shift[128];
    const int tid = threadIdx.x;
    if (tid < 128) {
        const float invn = 1.0f / (float)n;
        const float mean = stats[tid] * invn;
        const float var  = stats[128 + tid] * invn - mean * mean;
        const float inv  = rsqrtf(var + BN_EPS);
        const float g    = gamma[tid] * inv;
        s_scale[tid] = g;
        s_shift[tid] = beta[tid] - mean * g;
    }
    __syncthreads();

    float4* h4 = (float4*)h;
    const size_t total = (size_t)n * D / 4;
    const size_t stride = (size_t)gridDim.x * blockDim.x;
    for (size_t i = (size_t)blockIdx.x * blockDim.x + tid; i < total; i += stride) {
        float4 v = h4[i];
        const int c = (int)((i * 4) & (D - 1));
        v.x = v.x * s_scale[c]     + s_shift[c];
        v.y = v.y * s_scale[c + 1] + s_shift[c + 1];
        v.z = v.z * s_scale[c + 2] + s_shift[c + 2];
        v.w = v.w * s_scale[c + 3] + s_shift[c + 3];
        h4[i] = v;
    }
}

// ---------------------------------------------------------------------------
extern "C" void kernel_launch(void* const* d_in, const int* in_sizes, int n_in,
                              void* d_out, int out_size, void* d_ws, size_t ws_size,
                              hipStream_t stream)
{
    const float* x     = (const float*)d_in[0];
    const int*   esrc  = (const int*)d_in[1];
    const int*   edst  = (const int*)d_in[2];
    const float* evals = (const float*)d_in[3];
    const float* W     = (const float*)d_in[4];
    // d_in[5] = bias: unused — cancels exactly under BatchNorm.
    const float* gamma = (const float*)d_in[6];
    const float* beta  = (const float*)d_in[7];
    float* out = (float*)d_out;

    const int n = in_sizes[0] / D;   // 100000
    const int E = in_sizes[1];       // 1600000

    // Workspace layout (all 4-byte elements):
    //   agg      [n*D]    51.2 MB
    //   cnt      [n]      0.4 MB   (zeroed)
    //   stats    [256]             (zeroed, same memset)
    //   rowptr   [n]      0.4 MB
    //   csr_src  [E]      6.4 MB
    //   csr_val  [E]      6.4 MB
    float* agg     = (float*)d_ws;
    int*   cnt     = (int*)(agg + (size_t)n * D);
    float* stats   = (float*)(cnt + n);
    int*   rowptr  = (int*)(stats + 256);
    int*   csr_src = rowptr + n;
    float* csr_val = (float*)(csr_src + E);
    const size_t need = ((size_t)n * D + n + 256 + n + 2 * (size_t)E) * 4;

    if (ws_size >= need) {
        // zero cnt + stats only (agg is fully overwritten by spmm_csr)
        hipMemsetAsync(cnt, 0, ((size_t)n + 256) * 4, stream);
        hist_kernel<<<(E + 255) / 256, 256, 0, stream>>>(edst, cnt, E);
        scan_kernel<<<1, 1024, 0, stream>>>(cnt, rowptr, n);
        scatter_kernel<<<(E + 255) / 256, 256, 0, stream>>>(
            esrc, edst, evals, rowptr, csr_src, csr_val, E);
        spmm_csr_kernel<<<(n * 64 + 255) / 256, 256, 0, stream>>>(
            x, rowptr, csr_src, csr_val, agg, n);
    } else {
        // fallback: atomic scatter (round-1 path)
        hipMemsetAsync(d_ws, 0, ((size_t)n * D + n + 256) * 4, stream);
        spmm_atomic_kernel<<<4096, 256, 0, stream>>>(x, esrc, edst, evals, agg, E);
    }

    gemm_stats_kernel<<<(n + 31) / 32, 256, 0, stream>>>(agg, W, out, stats, n);
    bn_apply_kernel<<<2048, 256, 0, stream>>>(out, stats, gamma, beta, n);
}

// Round 3
// 496.735 us; speedup vs baseline: 3.0816x; 1.3497x over previous
//
#include <hip/hip_runtime.h>
#include <math.h>

// Problem constants: N=100000, E=1600000, D_IN=D_OUT=128
#define D 128
constexpr float BN_EPS = 1e-5f;

// bf16 helpers (manual, RNE) ------------------------------------------------
__device__ __forceinline__ unsigned f2bf_rne(float f) {
    unsigned u = __float_as_uint(f);
    return (u + 0x7FFFu + ((u >> 16) & 1u)) >> 16;
}
__device__ __forceinline__ float bf_lo(unsigned u) { return __uint_as_float(u << 16); }
__device__ __forceinline__ float bf_hi(unsigned u) { return __uint_as_float(u & 0xFFFF0000u); }

// ---------------------------------------------------------------------------
// Convert x (fp32 [n,128]) -> packed bf16 words xb [n,64] (word w = cols 2w,2w+1)
// ---------------------------------------------------------------------------
__global__ __launch_bounds__(256) void convert_x_kernel(
    const float4* __restrict__ x4, uint2* __restrict__ xb2, size_t nquads)
{
    size_t i = (size_t)blockIdx.x * blockDim.x + threadIdx.x;
    size_t stride = (size_t)gridDim.x * blockDim.x;
    for (; i < nquads; i += stride) {
        float4 v = x4[i];
        uint2 o;
        o.x = f2bf_rne(v.x) | (f2bf_rne(v.y) << 16);
        o.y = f2bf_rne(v.z) | (f2bf_rne(v.w) << 16);
        xb2[i] = o;
    }
}

// ---------------------------------------------------------------------------
// CSR build step 1: histogram of edge destinations.
// ---------------------------------------------------------------------------
__global__ __launch_bounds__(256) void hist_kernel(
    const int* __restrict__ edst, int* __restrict__ cnt, int E)
{
    int e = blockIdx.x * blockDim.x + threadIdx.x;
    if (e < E) atomicAdd(&cnt[edst[e]], 1);
}

// ---------------------------------------------------------------------------
// Multi-block exclusive scan of cnt[n] -> rowptr[n].
// Pass 1: per-block (1024-elem chunk) sums. Pass 2: 1-block exclusive scan of
// the ~98 block sums. Pass 3: per-block local exclusive scan + block offset.
// ---------------------------------------------------------------------------
__global__ __launch_bounds__(256) void scan_part_kernel(
    const int* __restrict__ cnt, int* __restrict__ bsum, int n)
{
    __shared__ int red[256];
    const int tid = threadIdx.x;
    const int base = blockIdx.x * 1024 + tid * 4;
    int s = 0;
#pragma unroll
    for (int i = 0; i < 4; i++) { int idx = base + i; if (idx < n) s += cnt[idx]; }
    red[tid] = s;
    __syncthreads();
    for (int off = 128; off > 0; off >>= 1) {
        if (tid < off) red[tid] += red[tid + off];
        __syncthreads();
    }
    if (tid == 0) bsum[blockIdx.x] = red[0];
}

__global__ __launch_bounds__(256) void scan_mid_kernel(int* __restrict__ bsum, int nb)
{
    __shared__ int sm[256];
    const int tid = threadIdx.x;
    int v = (tid < nb) ? bsum[tid] : 0;
    sm[tid] = v;
    __syncthreads();
    for (int off = 1; off < 256; off <<= 1) {
        int t = (tid >= off) ? sm[tid - off] : 0;
        __syncthreads();
        sm[tid] += t;
        __syncthreads();
    }
    if (tid < nb) bsum[tid] = sm[tid] - v;   // exclusive
}

__global__ __launch_bounds__(256) void scan_final_kernel(
    const int* __restrict__ cnt, const int* __restrict__ bsum,
    int* __restrict__ rowptr, int n)
{
    __shared__ int part[256];
    const int tid = threadIdx.x;
    const int base = blockIdx.x * 1024 + tid * 4;
    int v[4];
    int s = 0;
#pragma unroll
    for (int i = 0; i < 4; i++) {
        int idx = base + i;
        v[i] = (idx < n) ? cnt[idx] : 0;
        s += v[i];
    }
    part[tid] = s;
    __syncthreads();
    for (int off = 1; off < 256; off <<= 1) {
        int t = (tid >= off) ? part[tid - off] : 0;
        __syncthreads();
        part[tid] += t;
        __syncthreads();
    }
    int run = bsum[blockIdx.x] + part[tid] - s;   // exclusive prefix
#pragma unroll
    for (int i = 0; i < 4; i++) {
        int idx = base + i;
        if (idx < n) rowptr[idx] = run;
        run += v[i];
    }
}

// ---------------------------------------------------------------------------
// CSR build step 3: scatter edges (packed {src, val_bits}) into CSR order.
// rowptr is used as the fill cursor: afterwards rowptr[d] == end of row d.
// ---------------------------------------------------------------------------
__global__ __launch_bounds__(256) void scatter_kernel(
    const int* __restrict__ esrc, const int* __restrict__ edst,
    const float* __restrict__ evals,
    int* __restrict__ rowptr, int2* __restrict__ csr, int E)
{
    int e = blockIdx.x * blockDim.x + threadIdx.x;
    if (e < E) {
        int d = edst[e];
        int pos = atomicAdd(&rowptr[d], 1);
        csr[pos] = make_int2(esrc[e], __float_as_int(evals[e]));
    }
}

// ---------------------------------------------------------------------------
// CSR SpMM with bf16 x gather: one wave per dst row; lane handles 2 columns
// (one packed bf16x2 word = 4B/lane, 256B/row). 4-edge unroll for ILP.
// ---------------------------------------------------------------------------
__global__ __launch_bounds__(256) void spmm_csr_bf16_kernel(
    const unsigned* __restrict__ xb,
    const int* __restrict__ rowptr,   // post-scatter (end-pointer) form
    const int2* __restrict__ csr,
    float* __restrict__ agg, int n)
{
    int wave = (blockIdx.x * blockDim.x + threadIdx.x) >> 6;
    int lane = threadIdx.x & 63;
    if (wave >= n) return;
    int start = (wave == 0) ? 0 : rowptr[wave - 1];
    int end   = rowptr[wave];

    float ax = 0.f, ay = 0.f;
    int e = start;
    for (; e + 3 < end; e += 4) {
        int2 e0 = csr[e], e1 = csr[e + 1], e2 = csr[e + 2], e3 = csr[e + 3];
        unsigned u0 = xb[(size_t)e0.x * 64 + lane];
        unsigned u1 = xb[(size_t)e1.x * 64 + lane];
        unsigned u2 = xb[(size_t)e2.x * 64 + lane];
        unsigned u3 = xb[(size_t)e3.x * 64 + lane];
        float v0 = __int_as_float(e0.y), v1 = __int_as_float(e1.y);
        float v2 = __int_as_float(e2.y), v3 = __int_as_float(e3.y);
        ax += v0 * bf_lo(u0) + v1 * bf_lo(u1) + v2 * bf_lo(u2) + v3 * bf_lo(u3);
        ay += v0 * bf_hi(u0) + v1 * bf_hi(u1) + v2 * bf_hi(u2) + v3 * bf_hi(u3);
    }
    for (; e < end; e++) {
        int2 ed = csr[e];
        unsigned u = xb[(size_t)ed.x * 64 + lane];
        float v = __int_as_float(ed.y);
        ax += v * bf_lo(u);
        ay += v * bf_hi(u);
    }
    ((float2*)(agg + (size_t)wave * D))[lane] = make_float2(ax, ay);
}

// ---------------------------------------------------------------------------
// Fallback SpMM (atomic scatter) if ws_size is too small for CSR arrays.
// ---------------------------------------------------------------------------
__global__ __launch_bounds__(256) void spmm_atomic_kernel(
    const float* __restrict__ x,
    const int* __restrict__ esrc, const int* __restrict__ edst,
    const float* __restrict__ eval, float* __restrict__ agg, int E)
{
    int wave  = (blockIdx.x * blockDim.x + threadIdx.x) >> 6;
    int lane  = threadIdx.x & 63;
    int nwave = (gridDim.x * blockDim.x) >> 6;
    for (int e = wave; e < E; e += nwave) {
        int   s = esrc[e];
        int   d = edst[e];
        float v = eval[e];
        const float2 xv = ((const float2*)(x + (size_t)s * D))[lane];
        float* ar = agg + (size_t)d * D + lane * 2;
        atomicAdd(ar,     xv.x * v);
        atomicAdd(ar + 1, xv.y * v);
    }
}

// ---------------------------------------------------------------------------
// GEMM h = agg @ W with fused per-column sum / sum-of-squares epilogue.
// Block = 256 threads -> 32 rows x 128 cols tile. W (64KB) + A tile (16KB)
// in LDS = 80KB -> 2 blocks/CU.
// ---------------------------------------------------------------------------
__global__ __launch_bounds__(256) void gemm_stats_kernel(
    const float* __restrict__ A,
    const float* __restrict__ W,
    float* __restrict__ h,
    float* __restrict__ stats,   // [0..127]=colsum, [128..255]=colsumsq
    int n)
{
    __shared__ float sW[128 * 128];
    __shared__ float sA[32][128];

    const int tid = threadIdx.x;

    const float4* W4  = (const float4*)W;
    float4*       sW4 = (float4*)sW;
#pragma unroll
    for (int i = 0; i < 16; i++) sW4[tid + 256 * i] = W4[tid + 256 * i];

    const int row0 = blockIdx.x * 32;
    const float4* A4  = (const float4*)(A + (size_t)row0 * D);
    float4*       sA4 = (float4*)&sA[0][0];
#pragma unroll
    for (int i = 0; i < 4; i++) {
        int idx = tid + 256 * i;
        sA4[idx] = ((size_t)row0 * D + (size_t)idx * 4 < (size_t)n * D)
                       ? A4[idx] : make_float4(0.f, 0.f, 0.f, 0.f);
    }
    __syncthreads();

    const int tx = tid & 31;   // 32 col-groups of 4
    const int ty = tid >> 5;   // 8 row slots (rows ty, ty+8, ty+16, ty+24)
    const int c0 = tx * 4;

    float acc[4][4] = {};
    for (int k0 = 0; k0 < 128; k0 += 4) {
        float4 a[4];
#pragma unroll
        for (int j = 0; j < 4; j++)
            a[j] = *(const float4*)&sA[ty + 8 * j][k0];   // wave-broadcast
#pragma unroll
        for (int kk = 0; kk < 4; kk++) {
            const float4 w = *(const float4*)&sW[(k0 + kk) * 128 + c0];
            const float ak[4] = { kk == 0 ? a[0].x : kk == 1 ? a[0].y : kk == 2 ? a[0].z : a[0].w,
                                  kk == 0 ? a[1].x : kk == 1 ? a[1].y : kk == 2 ? a[1].z : a[1].w,
                                  kk == 0 ? a[2].x : kk == 1 ? a[2].y : kk == 2 ? a[2].z : a[2].w,
                                  kk == 0 ? a[3].x : kk == 1 ? a[3].y : kk == 2 ? a[3].z : a[3].w };
#pragma unroll
            for (int j = 0; j < 4; j++) {
                acc[j][0] += ak[j] * w.x;
                acc[j][1] += ak[j] * w.y;
                acc[j][2] += ak[j] * w.z;
                acc[j][3] += ak[j] * w.w;
            }
        }
    }

#pragma unroll
    for (int j = 0; j < 4; j++) {
        const int row = row0 + ty + 8 * j;
        if (row < n)
            *(float4*)&h[(size_t)row * D + c0] =
                make_float4(acc[j][0], acc[j][1], acc[j][2], acc[j][3]);
    }

    // fused column stats: reuse sA as scratch (all reads of sA are done)
    __syncthreads();
    float* csum = &sA[0][0];
    float* csq  = csum + 128;
    if (tid < 128) { csum[tid] = 0.f; csq[tid] = 0.f; }
    __syncthreads();
#pragma unroll
    for (int c = 0; c < 4; c++) {
        float s = 0.f, q = 0.f;
#pragma unroll
        for (int j = 0; j < 4; j++) { s += acc[j][c]; q += acc[j][c] * acc[j][c]; }
        atomicAdd(&csum[c0 + c], s);
        atomicAdd(&csq[c0 + c], q);
    }
    __syncthreads();
    if (tid < 128) {
        atomicAdd(&stats[tid],       csum[tid]);
        atomicAdd(&stats[128 + tid], csq[tid]);
    }
}

// ---------------------------------------------------------------------------
// In-place BatchNorm apply. Linear bias cancels under BN -> omitted.
// ---------------------------------------------------------------------------
__global__ __launch_bounds__(256) void bn_apply_kernel(
    float* __restrict__ h,
    const float* __restrict__ stats,
    const float* __restrict__ gamma,
    const float* __restrict__ beta,
    int n)
{
    __shared__ float s_scale[128];
    __shared__ float s_shift[128];
    const int tid = threadIdx.x;
    if (tid < 128) {
        const float invn = 1.0f / (float)n;
        const float mean = stats[tid] * invn;
        const float var  = stats[128 + tid] * invn - mean * mean;
        const float inv  = rsqrtf(var + BN_EPS);
        const float g    = gamma[tid] * inv;
        s_scale[tid] = g;
        s_shift[tid] = beta[tid] - mean * g;
    }
    __syncthreads();

    float4* h4 = (float4*)h;
    const size_t total = (size_t)n * D / 4;
    const size_t stride = (size_t)gridDim.x * blockDim.x;
    for (size_t i = (size_t)blockIdx.x * blockDim.x + tid; i < total; i += stride) {
        float4 v = h4[i];
        const int c = (int)((i * 4) & (D - 1));
        v.x = v.x * s_scale[c]     + s_shift[c];
        v.y = v.y * s_scale[c + 1] + s_shift[c + 1];
        v.z = v.z * s_scale[c + 2] + s_shift[c + 2];
        v.w = v.w * s_scale[c + 3] + s_shift[c + 3];
        h4[i] = v;
    }
}

// ---------------------------------------------------------------------------
extern "C" void kernel_launch(void* const* d_in, const int* in_sizes, int n_in,
                              void* d_out, int out_size, void* d_ws, size_t ws_size,
                              hipStream_t stream)
{
    const float* x     = (const float*)d_in[0];
    const int*   esrc  = (const int*)d_in[1];
    const int*   edst  = (const int*)d_in[2];
    const float* evals = (const float*)d_in[3];
    const float* W     = (const float*)d_in[4];
    // d_in[5] = bias: unused — cancels exactly under BatchNorm.
    const float* gamma = (const float*)d_in[6];
    const float* beta  = (const float*)d_in[7];
    float* out = (float*)d_out;

    const int n = in_sizes[0] / D;   // 100000
    const int E = in_sizes[1];       // 1600000

    // Workspace layout (word-indexed):
    //   agg    [n*D]  fp32   51.2 MB
    //   xb     [n*64] u32    25.6 MB (packed bf16 x)
    //   cnt    [n]           0.4 MB  (zeroed)
    //   stats  [256]                 (zeroed, same memset)
    //   rowptr [n]           0.4 MB
    //   bsum   [128]
    //   csr    [E] int2      12.8 MB (8B-aligned: offset is even #words)
    float*    agg    = (float*)d_ws;
    unsigned* xb     = (unsigned*)(agg + (size_t)n * D);
    int*      cnt    = (int*)(xb + (size_t)n * 64);
    float*    stats  = (float*)(cnt + n);
    int*      rowptr = (int*)(stats + 256);
    int*      bsum   = rowptr + n;
    int2*     csr    = (int2*)(bsum + 128);
    const size_t need = ((size_t)n * D + (size_t)n * 64 + n + 256 + n + 128) * 4
                        + (size_t)E * 8;

    const int nscan = (n + 1023) / 1024;   // 98 blocks (<=256 required)

    if (ws_size >= need && nscan <= 256) {
        hipMemsetAsync(cnt, 0, ((size_t)n + 256) * 4, stream);
        convert_x_kernel<<<4096, 256, 0, stream>>>(
            (const float4*)x, (uint2*)xb, (size_t)n * D / 4);
        hist_kernel<<<(E + 255) / 256, 256, 0, stream>>>(edst, cnt, E);
        scan_part_kernel<<<nscan, 256, 0, stream>>>(cnt, bsum, n);
        scan_mid_kernel<<<1, 256, 0, stream>>>(bsum, nscan);
        scan_final_kernel<<<nscan, 256, 0, stream>>>(cnt, bsum, rowptr, n);
        scatter_kernel<<<(E + 255) / 256, 256, 0, stream>>>(
            esrc, edst, evals, rowptr, csr, E);
        spmm_csr_bf16_kernel<<<(n + 3) / 4, 256, 0, stream>>>(
            xb, rowptr, csr, agg, n);
    } else {
        // fallback: atomic scatter (round-1 path)
        hipMemsetAsync(d_ws, 0, ((size_t)n * D + 256) * 4, stream);
        float* st = (float*)(agg + (size_t)n * D);
        spmm_atomic_kernel<<<4096, 256, 0, stream>>>(x, esrc, edst, evals, agg, E);
        gemm_stats_kernel<<<(n + 31) / 32, 256, 0, stream>>>(agg, W, out, st, n);
        bn_apply_kernel<<<2048, 256, 0, stream>>>(out, st, gamma, beta, n);
        return;
    }

    gemm_stats_kernel<<<(n + 31) / 32, 256, 0, stream>>>(agg, W, out, stats, n);
    bn_apply_kernel<<<2048, 256, 0, stream>>>(out, stats, gamma, beta, n);
}